// Round 9
// baseline (1871.596 us; speedup 1.0000x reference)
//
#include <hip/hip_runtime.h>

#define B_ 16
#define N_ 1024
#define M_ 4096
#define D_ 64
#define STEPS_ 576                      // 72 blocks of 8 (575 valid + 1 pad)
#define TILEF_ ((size_t)STEPS_ * 512)   // floats per tile buffer
#define TSB2_ ((size_t)STEPS_ * 128)    // dec bytes per tile
#define BTQ_ 96                         // backtrack window quads (384 cells)

__device__ __forceinline__ float finf() { return __builtin_inff(); }

// wave-wide shift right by 1 lane; lane 0 gets old (0), always select-overridden.
__device__ __forceinline__ float wave_shr1(float x) {
  return __int_as_float(__builtin_amdgcn_update_dpp(
      0, __float_as_int(x), 0x138, 0xF, 0xF, false));
}
__device__ __forceinline__ float rdlane(float v, int l) {
  return __int_as_float(__builtin_amdgcn_readlane(__float_as_int(v), l));
}

// ---------------------------------------------------------------------------
__global__ void prep_kernel(const float* __restrict__ x,
                            const float* __restrict__ x_t,
                            float* __restrict__ x2,
                            float* __restrict__ w_ts_out) {
  int id = blockIdx.x * blockDim.x + threadIdx.x;
  const float4* xr = (const float4*)(x + (size_t)id * D_);
  float s = 0.f;
#pragma unroll
  for (int e = 0; e < D_ / 4; ++e) {
    float4 v = xr[e];
    s += v.x * v.x + v.y * v.y + v.z * v.z + v.w * v.w;
  }
  x2[id] = s;
  w_ts_out[id] = x_t[id];
}

// ---------------------------------------------------------------------------
// GEMM writing C skewed for the 2-row systolic DP: cell (i, ct) of a 256-col
// tile lands at Cs[tile][s*512 + (i&1)*256 + ct], s = (ct>>2) + (i>>1).
// ---------------------------------------------------------------------------
__global__ __launch_bounds__(256) void gemm_kernel(
    const float* __restrict__ x, const float* __restrict__ y,
    const float* __restrict__ x2, float* __restrict__ Cs,
    int chunkBase, int NT) {
  const int b = blockIdx.z;
  const int tile = blockIdx.x;
  const int lane = threadIdx.x & 63;
  const int wid = threadIdx.x >> 6;
  const int ct = wid * 64 + lane;
  const int j = chunkBase + tile * 256 + ct;
  const int l = ct >> 2;
  float* CsT = Cs + (size_t)(b * NT + tile) * TILEF_;

  const float4* yrow = (const float4*)(y + ((size_t)b * M_ + j) * D_);
  float4 yr[D_ / 4];
#pragma unroll
  for (int e = 0; e < D_ / 4; ++e) yr[e] = yrow[e];
  float y2 = 0.f;
#pragma unroll
  for (int e = 0; e < D_ / 4; ++e)
    y2 += yr[e].x * yr[e].x + yr[e].y * yr[e].y + yr[e].z * yr[e].z + yr[e].w * yr[e].w;

  const int ibeg = blockIdx.y * 128;
  for (int i = ibeg; i < ibeg + 128; ++i) {
    const float4* xr = (const float4*)(x + ((size_t)b * N_ + i) * D_);
    float acc = 0.f;
#pragma unroll
    for (int e = 0; e < D_ / 4; ++e) {
      float4 xv = xr[e];
      acc += xv.x * yr[e].x + xv.y * yr[e].y + xv.z * yr[e].z + xv.w * yr[e].w;
    }
    const int s = l + (i >> 1);
    CsT[(size_t)s * 512 + (i & 1) * 256 + ct] = x2[b * N_ + i] + y2 - 2.f * acc;
  }
}

// ---------------------------------------------------------------------------
// Systolic DP, 2 rows x 4 cols per lane per step. 2 independent batches per
// WG (2 pipelines of NT waves). Lane l, step s -> rows 2(s-l), 2(s-l)+1 of
// its 4 cols. Neighbor deps via 2 DPP row-tails (shA/shB, 1- and 2-step old).
// Full-column LDS edge ring, publish/poll once per 8-step block.
// dec: 1 ushort/lane/step = rowA codes (low byte) + rowB codes (high byte).
// ---------------------------------------------------------------------------
template <int NT>
__global__ __launch_bounds__(512) void dtw_dp(
    const float* __restrict__ Cs, unsigned char* __restrict__ dec,
    const float* __restrict__ carryIn, float* __restrict__ carryOut,
    float* __restrict__ partV, int* __restrict__ partJ,
    int chunk, int nch, int hasCarry) {
  const int t = threadIdx.x;
  const int g = t / (NT * 64);
  const int tg = t % (NT * 64);
  const int lane = tg & 63;
  const int W = tg >> 6;
  const int b = blockIdx.x * 2 + g;

  __shared__ float ring[2][NT - 1 > 0 ? NT - 1 : 1][1024];
  __shared__ float cring[2][1024];
  __shared__ int prog[2][NT - 1 > 0 ? NT - 1 : 1];
  __shared__ float redV[2][NT];
  __shared__ int redJ[2][NT];
  volatile int* vProgG = prog[g];

  if (tg < NT - 1) prog[g][tg] = -1;
  const float* cIn = carryIn + b * N_;
  if (hasCarry) {
    for (int k = tg; k < 256; k += NT * 64)
      ((float4*)cring[g])[k] = ((const float4*)cIn)[k];
  }
  __syncthreads();

  const float INF = finf();
  const float* tileBase = Cs + (size_t)(b * NT + W) * TILEF_;
  const float* loadP = tileBase + 8 * 512;
  const float* loadMax = tileBase + (STEPS_ - 8) * 512;
  const int tileG = chunk * NT + W;
  char* decBase = (char*)(dec + (size_t)(b * 16 + tileG) * TSB2_);
  float* carryB = carryOut + b * N_;
  const int jbase = tileG * 256 + lane * 4;
  const float* ringR = ring[g][W > 0 ? W - 1 : 0];
  volatile float* ringW = ring[g][W < NT - 1 ? W : 0];
  const float* cringG = cring[g];
  const bool doCarry = (W == NT - 1) && (chunk < nch - 1);

  float4 a0 = ((const float4*)(tileBase + 0 * 512))[lane];
  float4 b0 = ((const float4*)(tileBase + 0 * 512 + 256))[lane];
  float4 a1 = ((const float4*)(tileBase + 1 * 512))[lane];
  float4 b1 = ((const float4*)(tileBase + 1 * 512 + 256))[lane];
  float4 a2 = ((const float4*)(tileBase + 2 * 512))[lane];
  float4 b2 = ((const float4*)(tileBase + 2 * 512 + 256))[lane];
  float4 a3 = ((const float4*)(tileBase + 3 * 512))[lane];
  float4 b3 = ((const float4*)(tileBase + 3 * 512 + 256))[lane];
  float4 a4 = ((const float4*)(tileBase + 4 * 512))[lane];
  float4 b4 = ((const float4*)(tileBase + 4 * 512 + 256))[lane];
  float4 a5 = ((const float4*)(tileBase + 5 * 512))[lane];
  float4 b5 = ((const float4*)(tileBase + 5 * 512 + 256))[lane];
  float4 a6 = ((const float4*)(tileBase + 6 * 512))[lane];
  float4 b6 = ((const float4*)(tileBase + 6 * 512 + 256))[lane];
  float4 a7 = ((const float4*)(tileBase + 7 * 512))[lane];
  float4 b7 = ((const float4*)(tileBase + 7 * 512 + 256))[lane];

  float upB0 = 0.f, upB1 = 0.f, upB2 = 0.f, upB3 = 0.f;
  float shA1 = INF, shB1 = INF, shB2 = INF;
  float edgeVec = INF;
  float fin0 = INF, fin1 = INF, fin2 = INF, fin3 = INF;
  float ebA[8], ebB[8];

#define BLOCKHEAD()                                                           \
  {                                                                           \
    if (2 * sb < N_) {                                                        \
      if (W > 0) {                                                            \
        int tgt = 2 * sb + 15;                                                \
        if (tgt > N_ - 1) tgt = N_ - 1;                                       \
        while (vProgG[W - 1] < tgt) __builtin_amdgcn_s_sleep(1);              \
        asm volatile("" ::: "memory");                                        \
        edgeVec = ringR[(2 * sb - 1 + lane) & 1023];                          \
      } else if (hasCarry) {                                                  \
        edgeVec = cringG[(2 * sb - 1 + lane) & 1023];                         \
      }                                                                       \
    }                                                                         \
  }

#define DPSTEP(KK, CA, CB, ROW0, FIN)                                         \
  {                                                                           \
    const float dA0e = rdlane(edgeVec, 2 * (KK));                             \
    const float lA0e = rdlane(edgeVec, 2 * (KK) + 1);                         \
    const float lB0e = rdlane(edgeVec, 2 * (KK) + 2);                         \
    const bool l0 = (lane == 0);                                              \
    const float lA0 = l0 ? lA0e : shA1;                                       \
    const float dA0 = l0 ? dA0e : shB2;                                       \
    const float lB0 = l0 ? lB0e : shB1;                                       \
    const float dB0 = lA0;                                                    \
    float m, bv;                                                              \
    m = fminf(upB0, lA0); bv = fminf(dA0, m);                                 \
    unsigned int pk = (dA0 <= m) ? 0u : ((upB0 <= lA0) ? 1u : 2u);            \
    if (ROW0) bv = (sb + (KK) == lane) ? 0.f : bv;                            \
    const float DA0 = CA.x + bv;                                              \
    m = fminf(upB1, DA0); bv = fminf(upB0, m);                                \
    pk |= ((upB0 <= m) ? 0u : ((upB1 <= DA0) ? 1u : 2u)) << 2;                \
    if (ROW0) bv = (sb + (KK) == lane) ? 0.f : bv;                            \
    const float DA1 = CA.y + bv;                                              \
    m = fminf(upB2, DA1); bv = fminf(upB1, m);                                \
    pk |= ((upB1 <= m) ? 0u : ((upB2 <= DA1) ? 1u : 2u)) << 4;                \
    if (ROW0) bv = (sb + (KK) == lane) ? 0.f : bv;                            \
    const float DA2 = CA.z + bv;                                              \
    m = fminf(upB3, DA2); bv = fminf(upB2, m);                                \
    pk |= ((upB2 <= m) ? 0u : ((upB3 <= DA2) ? 1u : 2u)) << 6;                \
    if (ROW0) bv = (sb + (KK) == lane) ? 0.f : bv;                            \
    const float DA3 = CA.w + bv;                                              \
    m = fminf(DA0, lB0); bv = fminf(dB0, m);                                  \
    pk |= ((dB0 <= m) ? 0u : ((DA0 <= lB0) ? 1u : 2u)) << 8;                  \
    const float DB0 = CB.x + bv;                                              \
    m = fminf(DA1, DB0); bv = fminf(DA0, m);                                  \
    pk |= ((DA0 <= m) ? 0u : ((DA1 <= DB0) ? 1u : 2u)) << 10;                 \
    const float DB1 = CB.y + bv;                                              \
    m = fminf(DA2, DB1); bv = fminf(DA1, m);                                  \
    pk |= ((DA1 <= m) ? 0u : ((DA2 <= DB1) ? 1u : 2u)) << 12;                 \
    const float DB2 = CB.z + bv;                                              \
    m = fminf(DA3, DB2); bv = fminf(DA2, m);                                  \
    pk |= ((DA2 <= m) ? 0u : ((DA3 <= DB2) ? 1u : 2u)) << 14;                 \
    const float DB3 = CB.w + bv;                                              \
    *(unsigned short*)(decBase + (KK) * 128 + (lane << 1)) =                  \
        (unsigned short)pk;                                                   \
    ebA[(KK)] = DA3; ebB[(KK)] = DB3;                                         \
    if (FIN) {                                                                \
      const bool lr = (sb + (KK) == 511 + lane);                              \
      fin0 = lr ? DB0 : fin0; fin1 = lr ? DB1 : fin1;                         \
      fin2 = lr ? DB2 : fin2; fin3 = lr ? DB3 : fin3;                         \
    }                                                                         \
    shB2 = shB1;                                                              \
    shA1 = wave_shr1(DA3);                                                    \
    shB1 = wave_shr1(DB3);                                                    \
    upB0 = DB0; upB1 = DB1; upB2 = DB2; upB3 = DB3;                           \
    CA = ((const float4*)(loadP + (KK) * 512))[lane];                         \
    CB = ((const float4*)(loadP + (KK) * 512 + 256))[lane];                   \
  }

#define BLOCKEND()                                                            \
  {                                                                           \
    const int rb = 2 * (sb - 63);                                             \
    if (W < NT - 1) {                                                         \
      if (lane == 63 && rb >= -14) {                                          \
        _Pragma("unroll") for (int k = 0; k < 8; ++k) {                       \
          const int r = rb + 2 * k;                                           \
          if ((unsigned)r < (unsigned)N_) ringW[r] = ebA[k];                  \
          if ((unsigned)(r + 1) < (unsigned)N_) ringW[r + 1] = ebB[k];        \
        }                                                                     \
        __builtin_amdgcn_s_waitcnt(0xC07F);                                   \
        int p = rb + 15; if (p > N_ - 1) p = N_ - 1;                          \
        vProgG[W] = p;                                                        \
      }                                                                       \
    } else if (doCarry) {                                                     \
      if (lane == 63 && rb >= -14) {                                          \
        _Pragma("unroll") for (int k = 0; k < 8; ++k) {                       \
          const int r = rb + 2 * k;                                           \
          if ((unsigned)r < (unsigned)N_) carryB[r] = ebA[k];                 \
          if ((unsigned)(r + 1) < (unsigned)N_) carryB[r + 1] = ebB[k];       \
        }                                                                     \
      }                                                                       \
    }                                                                         \
    loadP += 8 * 512;                                                         \
    if (loadP > loadMax) loadP = loadMax;                                     \
    decBase += 1024;                                                          \
  }

#define STEP8(R0, FN)                                                         \
  DPSTEP(0, a0, b0, R0, FN) DPSTEP(1, a1, b1, R0, FN)                         \
  DPSTEP(2, a2, b2, R0, FN) DPSTEP(3, a3, b3, R0, FN)                         \
  DPSTEP(4, a4, b4, R0, FN) DPSTEP(5, a5, b5, R0, FN)                         \
  DPSTEP(6, a6, b6, R0, FN) DPSTEP(7, a7, b7, R0, FN)

  int sb = 0;
  for (int it = 0; it < 8; ++it) {   // sb 0..63: row-0 selects live
    BLOCKHEAD();
    STEP8(1, 0)
    BLOCKEND();
    sb += 8;
  }
  for (int it = 0; it < 55; ++it) {  // sb 64..503: main
    BLOCKHEAD();
    STEP8(0, 0)
    BLOCKEND();
    sb += 8;
  }
  for (int it = 0; it < 9; ++it) {   // sb 504..575: fin captures
    BLOCKHEAD();
    STEP8(0, 1)
    BLOCKEND();
    sb += 8;
  }
#undef DPSTEP
#undef STEP8
#undef BLOCKHEAD
#undef BLOCKEND

  float mv = fin0; int mj = jbase;
  if (fin1 < mv) { mv = fin1; mj = jbase + 1; }
  if (fin2 < mv) { mv = fin2; mj = jbase + 2; }
  if (fin3 < mv) { mv = fin3; mj = jbase + 3; }
#pragma unroll
  for (int off = 32; off > 0; off >>= 1) {
    const float ov = __shfl_down(mv, off);
    const int oj = __shfl_down(mj, off);
    if (ov < mv || (ov == mv && oj < mj)) { mv = ov; mj = oj; }
  }
  if (lane == 0) { redV[g][W] = mv; redJ[g][W] = mj; }
  __syncthreads();
  if (tg == 0) {
    float bm = redV[g][0]; int bj = redJ[g][0];
#pragma unroll
    for (int w = 1; w < NT; ++w)
      if (redV[g][w] < bm) { bm = redV[g][w]; bj = redJ[g][w]; }
    partV[b * 8 + chunk] = bm;
    partJ[b * 8 + chunk] = bj;
  }
}

// ---------------------------------------------------------------------------
// Backtrack (R8 structure): 4 threads/row x 64 rows per super-step. Byte for
// (row r, quad q): tile=q>>6, l=q&63, s=(r>>1)+l ->
//   db[tile*TSB2 + s*128 + l*2 + (r&1)].
// ---------------------------------------------------------------------------
__global__ __launch_bounds__(256) void backtrack_kernel(
    const unsigned char* __restrict__ dec, const float* __restrict__ partV,
    const int* __restrict__ partJ, int nch, const float* __restrict__ y_t,
    float* __restrict__ w_vs, float* __restrict__ cost_out) {
  const int b = blockIdx.x;
  const int t = threadIdx.x;
  const int rowIdx = t >> 2;
  const int sub = t & 3;
  __shared__ unsigned short tab[64][BTQ_ * 4 + 2];
  __shared__ unsigned short lastv[64][4];
  __shared__ int st_i, st_j;
  __shared__ int jrow[65];
  const unsigned char* db = dec + (size_t)b * 16 * TSB2_;
  const float* yt = y_t + b * M_;
  float* wv = w_vs + b * N_;

  if (t == 0) {
    float bc = finf(); int bj = 0;
    for (int c = 0; c < nch; ++c) {  // chunks ascend in j: strict < keeps first
      const float v = partV[b * 8 + c];
      if (v < bc) { bc = v; bj = partJ[b * 8 + c]; }
    }
    cost_out[b] = bc;
    st_i = N_ - 1;
    st_j = bj;
    wv[N_ - 1] = yt[bj];
  }
  for (;;) {
    __syncthreads();
    const int i = st_i, j = st_j;
    if (i <= 0) break;
    int qlo = (j >> 2) - (BTQ_ - 1);
    if (qlo < 0) qlo = 0;
    const int r = i - rowIdx;
    const int cbase = sub * 96;
    int patchEnd = 0;
    if (r >= 1) {
      unsigned char by[24];
      const int q0 = qlo + sub * 24;
#pragma unroll
      for (int k = 0; k < 24; ++k) {
        const int q = q0 + k;
        const int l = q & 63;
        const int s = (r >> 1) + l;
        by[k] = db[(size_t)(q >> 6) * TSB2_ + (size_t)s * 128 + l * 2 + (r & 1)];
      }
      unsigned int run = 0xFFFF;
      int fs = -1;
#pragma unroll
      for (int k = 0; k < 24; ++k) {
        const unsigned int byte = by[k];
#pragma unroll
        for (int cs = 0; cs < 4; ++cs) {
          const unsigned int code = (byte >> (2 * cs)) & 3u;
          const int cloc = 4 * k + cs;
          if (code != 2u) {
            run = (unsigned int)(((cbase + cloc) << 2) | code);
            if (fs < 0) fs = cloc;
          }
          tab[rowIdx][cbase + cloc] = (unsigned short)run;
        }
      }
      lastv[rowIdx][sub] = (unsigned short)run;
      patchEnd = (fs < 0) ? 96 : fs;
    }
    __syncthreads();
    if (r >= 1 && sub > 0 && patchEnd > 0) {
      unsigned short inc = 0xFFFF;
      for (int s2 = 0; s2 < sub; ++s2) {
        const unsigned short lv = lastv[rowIdx][s2];
        if (lv != 0xFFFF) inc = lv;
      }
      if (inc != 0xFFFF) {
        for (int k = 0; k < patchEnd; ++k) tab[rowIdx][cbase + k] = inc;
      }
    }
    __syncthreads();
    if (t == 0) {
      const int base = qlo << 2;
      int rr = i, cj = j;
      while (rr >= 1 && (i - rr) < 64) {
        const int l = i - rr;
        const int c = cj - base;
        if (c < 0) break;  // window exhausted; restart
        const unsigned short v = tab[l][c];
        if (v == 0xFFFF) { cj = base - 1; break; }  // left-run exits window
        cj = base + (int)(v >> 2) - (((v & 3) == 0) ? 1 : 0);
        --rr;
        jrow[i - rr] = cj;
      }
      st_i = rr;
      st_j = cj;
    }
    __syncthreads();
    const int cnt = i - st_i;
    if (t < cnt) wv[i - 1 - t] = yt[jrow[t + 1]];
  }
}

// ---------------------------------------------------------------------------
extern "C" void kernel_launch(void* const* d_in, const int* in_sizes, int n_in,
                              void* d_out, int out_size, void* d_ws, size_t ws_size,
                              hipStream_t stream) {
  const float* x = (const float*)d_in[0];
  const float* y = (const float*)d_in[1];
  const float* x_t = (const float*)d_in[2];
  const float* y_t = (const float*)d_in[3];

  float* out_cost = (float*)d_out;      // [B_]
  float* out_wts = out_cost + B_;       // [B_][N_]
  float* out_wvs = out_wts + B_ * N_;   // [B_][N_]

  const size_t decBytes = (size_t)B_ * 16 * TSB2_;         // 18.87 MB
  const size_t x2Bytes = (size_t)B_ * N_ * 4;
  const size_t cs4 = (size_t)B_ * 4 * TILEF_ * 4;          // 75.5 MB
  const size_t tail = x2Bytes + 2 * (size_t)B_ * N_ * 4 + B_ * 8 * 8;
  const size_t need4 = cs4 + decBytes + tail;

  const int NT = (ws_size >= need4) ? 4 : 2;
  const int NCH = 16 / NT;
  const size_t csBytes = (size_t)B_ * NT * TILEF_ * 4;

  char* ws = (char*)d_ws;
  float* Cs = (float*)ws;
  unsigned char* dec = (unsigned char*)(ws + csBytes);
  float* x2 = (float*)(ws + csBytes + decBytes);
  float* carryA = (float*)(ws + csBytes + decBytes + x2Bytes);
  float* carryB = carryA + B_ * N_;
  float* partV = carryB + B_ * N_;
  int* partJ = (int*)(partV + B_ * 8);

  prep_kernel<<<dim3((B_ * N_) / 256), 256, 0, stream>>>(x, x_t, x2, out_wts);

  float* cbuf[2] = {carryA, carryB};
  for (int c = 0; c < NCH; ++c) {
    gemm_kernel<<<dim3(NT, N_ / 128, B_), 256, 0, stream>>>(
        x, y, x2, Cs, c * NT * 256, NT);
    const float* cin = cbuf[(c + 1) & 1];
    float* cout = cbuf[c & 1];
    if (NT == 4) {
      dtw_dp<4><<<dim3(B_ / 2), 512, 0, stream>>>(Cs, dec, cin, cout, partV,
                                                  partJ, c, NCH, c > 0 ? 1 : 0);
    } else {
      dtw_dp<2><<<dim3(B_ / 2), 256, 0, stream>>>(Cs, dec, cin, cout, partV,
                                                  partJ, c, NCH, c > 0 ? 1 : 0);
    }
  }

  backtrack_kernel<<<dim3(B_), 256, 0, stream>>>(dec, partV, partJ, NCH, y_t,
                                                 out_wvs, out_cost);
}

// Round 10
// 1531.474 us; speedup vs baseline: 1.2221x; 1.2221x over previous
//
#include <hip/hip_runtime.h>

#define B_ 16
#define N_ 1024
#define M_ 4096
#define D_ 64
#define NTW 8                         // waves per batch pipeline
#define TROWS_ 1096                   // padded skewed rows per 128-col tile
#define TILEF_ ((size_t)TROWS_ * 128) // floats per tile buffer
#define TSB2_ ((size_t)548 * 64)      // dec bytes per tile (35072)
#define BTP_ 192                      // backtrack window pairs (384 cells)

__device__ __forceinline__ float finf() { return __builtin_inff(); }

// wave-wide shift right by 1 lane; lane 0 gets old (0), always select-overridden.
__device__ __forceinline__ float wave_shr1(float x) {
  return __int_as_float(__builtin_amdgcn_update_dpp(
      0, __float_as_int(x), 0x138, 0xF, 0xF, false));
}
__device__ __forceinline__ float rdlane(float v, int l) {
  return __int_as_float(__builtin_amdgcn_readlane(__float_as_int(v), l));
}

// ---------------------------------------------------------------------------
__global__ void prep_kernel(const float* __restrict__ x,
                            const float* __restrict__ x_t,
                            float* __restrict__ x2,
                            float* __restrict__ w_ts_out) {
  int id = blockIdx.x * blockDim.x + threadIdx.x;
  const float4* xr = (const float4*)(x + (size_t)id * D_);
  float s = 0.f;
#pragma unroll
  for (int e = 0; e < D_ / 4; ++e) {
    float4 v = xr[e];
    s += v.x * v.x + v.y * v.y + v.z * v.z + v.w * v.w;
  }
  x2[id] = s;
  w_ts_out[id] = x_t[id];
}

// ---------------------------------------------------------------------------
// GEMM writing C skewed for cpl=2 tiles of 128 cols: cell (i, col ctt of
// tile) -> CsT[(i + (ctt>>1))*128 + ctt].
// ---------------------------------------------------------------------------
__global__ __launch_bounds__(256) void gemm_kernel(
    const float* __restrict__ x, const float* __restrict__ y,
    const float* __restrict__ x2, float* __restrict__ Cs, int chunk) {
  const int b = blockIdx.z;
  const int tb = blockIdx.x;               // 256-col block within chunk
  const int lane = threadIdx.x & 63;
  const int wid = threadIdx.x >> 6;
  const int ct = wid * 64 + lane;          // 0..255
  const int j = chunk * 1024 + tb * 256 + ct;
  const int tileIdx = tb * 2 + (ct >> 7);  // tile within chunk (0..7)
  const int ctt = ct & 127;
  const int l = ctt >> 1;
  float* CsT = Cs + (size_t)(b * 8 + tileIdx) * TILEF_;

  const float4* yrow = (const float4*)(y + ((size_t)b * M_ + j) * D_);
  float4 yr[D_ / 4];
#pragma unroll
  for (int e = 0; e < D_ / 4; ++e) yr[e] = yrow[e];
  float y2 = 0.f;
#pragma unroll
  for (int e = 0; e < D_ / 4; ++e)
    y2 += yr[e].x * yr[e].x + yr[e].y * yr[e].y + yr[e].z * yr[e].z + yr[e].w * yr[e].w;

  const int ibeg = blockIdx.y * 128;
  for (int i = ibeg; i < ibeg + 128; ++i) {
    const float4* xr = (const float4*)(x + ((size_t)b * N_ + i) * D_);
    float acc = 0.f;
#pragma unroll
    for (int e = 0; e < D_ / 4; ++e) {
      float4 xv = xr[e];
      acc += xv.x * yr[e].x + xv.y * yr[e].y + xv.z * yr[e].z + xv.w * yr[e].w;
    }
    CsT[(size_t)(i + l) * 128 + ctt] = x2[b * N_ + i] + y2 - 2.f * acc;
  }
}

// ---------------------------------------------------------------------------
// Systolic DP, cpl=2: one batch per 512-thread WG (8 waves, 2/SIMD). Wave W
// owns a 128-col tile; lane l owns cols 2l,2l+1; step s => row i = s - lane.
// Full-column LDS edge ring (1024/row, written once), publish per 8 rows,
// poll once per block. dec: 4 bits/lane/step, 2 steps per byte.
// ---------------------------------------------------------------------------
__global__ __launch_bounds__(512) void dtw_dp(
    const float* __restrict__ Cs, unsigned char* __restrict__ dec,
    const float* __restrict__ carryIn, float* __restrict__ carryOut,
    float* __restrict__ partV, int* __restrict__ partJ,
    int chunk, int hasCarry) {
  const int b = blockIdx.x;
  const int t = threadIdx.x;
  const int lane = t & 63;
  const int W = t >> 6;

  __shared__ float ring[NTW - 1][1024];
  __shared__ float cring[1024];
  __shared__ int prog[NTW - 1];
  __shared__ float redV[NTW];
  __shared__ int redJ[NTW];
  volatile int* vProg = prog;

  if (t < NTW - 1) prog[t] = -1;
  const float* cIn = carryIn + b * N_;
  if (hasCarry && t < 256) ((float4*)cring)[t] = ((const float4*)cIn)[t];
  __syncthreads();

  const float INF = finf();
  const float* tileBase = Cs + (size_t)(b * 8 + W) * TILEF_;
  const float* loadP = tileBase + 8 * 128;
  const int tileG = chunk * 8 + W;
  unsigned char* decBase = dec + (size_t)(b * 32 + tileG) * TSB2_ + lane;
  float* carryB = carryOut + b * N_;
  const int jbase = tileG * 128 + lane * 2;
  const float* ringR = ring[W > 0 ? W - 1 : 0];
  volatile float* ringW = ring[W < NTW - 1 ? W : 0];
  const bool doCarry = (W == NTW - 1) && (chunk < 3);

  float2 cc0 = ((const float2*)(tileBase + 0 * 128))[lane];
  float2 cc1 = ((const float2*)(tileBase + 1 * 128))[lane];
  float2 cc2 = ((const float2*)(tileBase + 2 * 128))[lane];
  float2 cc3 = ((const float2*)(tileBase + 3 * 128))[lane];
  float2 cc4 = ((const float2*)(tileBase + 4 * 128))[lane];
  float2 cc5 = ((const float2*)(tileBase + 5 * 128))[lane];
  float2 cc6 = ((const float2*)(tileBase + 6 * 128))[lane];
  float2 cc7 = ((const float2*)(tileBase + 7 * 128))[lane];

  float edgeVec = INF, ePrev = INF;
  float up0 = 0.f, up1 = 0.f;
  float sh1 = INF, sh2 = INF;
  float fin0 = INF, fin1 = INF;
  float ebuf[8];

#define BLOCKHEAD()                                                           \
  {                                                                           \
    if (sb < N_) {                                                            \
      if (W > 0) {                                                            \
        int tgt = sb + 7;                                                     \
        if (tgt > N_ - 1) tgt = N_ - 1;                                       \
        while (vProg[W - 1] < tgt) __builtin_amdgcn_s_sleep(1);               \
        asm volatile("" ::: "memory");                                        \
        edgeVec = ringR[(sb - 1 + lane) & 1023];                              \
      } else if (hasCarry) {                                                  \
        edgeVec = cring[(sb - 1 + lane) & 1023];                              \
      }                                                                       \
      ePrev = rdlane(edgeVec, 0);                                             \
    }                                                                         \
  }

#define DPSTEP(KK, CCV, ROW0, FIN)                                           \
  {                                                                          \
    const float eL = rdlane(edgeVec, (KK) + 1);                              \
    const bool l0 = (lane == 0);                                             \
    const float left0 = l0 ? eL : sh1;                                       \
    const float diag0 = l0 ? ePrev : sh2;                                    \
    ePrev = eL;                                                              \
    float m = fminf(up0, left0);                                             \
    float bv = fminf(diag0, m);                                              \
    unsigned int pk = (diag0 <= m) ? 0u : ((up0 <= left0) ? 1u : 2u);        \
    if (ROW0) bv = (sb + (KK) == lane) ? 0.f : bv;                           \
    const float D0 = CCV.x + bv;                                             \
    m = fminf(up1, D0);                                                      \
    bv = fminf(up0, m);                                                      \
    pk |= ((up0 <= m) ? 0u : ((up1 <= D0) ? 1u : 2u)) << 2;                  \
    if (ROW0) bv = (sb + (KK) == lane) ? 0.f : bv;                           \
    const float D1 = CCV.y + bv;                                             \
    if ((KK) & 1) {                                                          \
      pkb |= pk << 4;                                                        \
      decBase[((KK) >> 1) * 64] = (unsigned char)pkb;                        \
    } else {                                                                 \
      pkb = pk;                                                              \
    }                                                                        \
    ebuf[(KK)] = D1;                                                         \
    if (FIN) {                                                               \
      const bool lr = (sb + (KK) == 1023 + lane);                            \
      fin0 = lr ? D0 : fin0;                                                 \
      fin1 = lr ? D1 : fin1;                                                 \
    }                                                                        \
    sh2 = sh1;                                                               \
    sh1 = wave_shr1(D1);                                                     \
    up0 = D0; up1 = D1;                                                      \
    CCV = ((const float2*)(loadP + (KK) * 128))[lane];                       \
  }

#define BLOCKEND()                                                           \
  {                                                                          \
    const int rb = sb - 63;                                                  \
    if (W < NTW - 1) {                                                       \
      if (lane == 63 && rb > -8) {                                           \
        _Pragma("unroll") for (int k = 0; k < 8; ++k) {                      \
          const int r = rb + k;                                              \
          if ((unsigned)r < (unsigned)N_) ringW[r] = ebuf[k];                \
        }                                                                    \
        __builtin_amdgcn_s_waitcnt(0xC07F);                                  \
        int p = rb + 7;                                                      \
        if (p > N_ - 1) p = N_ - 1;                                          \
        if (p >= 0) vProg[W] = p;                                            \
      }                                                                      \
    } else if (doCarry) {                                                    \
      if (lane == 63 && rb > -8) {                                           \
        _Pragma("unroll") for (int k = 0; k < 8; ++k) {                      \
          const int r = rb + k;                                              \
          if ((unsigned)r < (unsigned)N_) carryB[r] = ebuf[k];               \
        }                                                                    \
      }                                                                      \
    }                                                                        \
    loadP += 8 * 128;                                                        \
    decBase += 256;                                                          \
  }

#define STEP8(R0, FN)                                                        \
  DPSTEP(0, cc0, R0, FN) DPSTEP(1, cc1, R0, FN) DPSTEP(2, cc2, R0, FN)       \
  DPSTEP(3, cc3, R0, FN) DPSTEP(4, cc4, R0, FN) DPSTEP(5, cc5, R0, FN)       \
  DPSTEP(6, cc6, R0, FN) DPSTEP(7, cc7, R0, FN)

  int sb = 0;
  for (int it = 0; it < 8; ++it) {    // sb 0..63: row-0 selects live
    BLOCKHEAD();
    { unsigned int pkb; STEP8(1, 0) }
    BLOCKEND();
    sb += 8;
  }
  for (int it = 0; it < 119; ++it) {  // sb 64..1015: main
    BLOCKHEAD();
    { unsigned int pkb; STEP8(0, 0) }
    BLOCKEND();
    sb += 8;
  }
  for (int it = 0; it < 9; ++it) {    // sb 1016..1087: fin captures
    BLOCKHEAD();
    { unsigned int pkb; STEP8(0, 1) }
    BLOCKEND();
    sb += 8;
  }
#undef DPSTEP
#undef STEP8
#undef BLOCKHEAD
#undef BLOCKEND

  float mv = fin0; int mj = jbase;
  if (fin1 < mv) { mv = fin1; mj = jbase + 1; }
#pragma unroll
  for (int off = 32; off > 0; off >>= 1) {
    const float ov = __shfl_down(mv, off);
    const int oj = __shfl_down(mj, off);
    if (ov < mv || (ov == mv && oj < mj)) { mv = ov; mj = oj; }
  }
  if (lane == 0) { redV[W] = mv; redJ[W] = mj; }
  __syncthreads();
  if (t == 0) {
    float bm = redV[0]; int bj = redJ[0];
#pragma unroll
    for (int w = 1; w < NTW; ++w)
      if (redV[w] < bm) { bm = redV[w]; bj = redJ[w]; }
    partV[b * 4 + chunk] = bm;
    partJ[b * 4 + chunk] = bj;
  }
}

// ---------------------------------------------------------------------------
// Backtrack: 512 threads = 8 subs/row x 64 rows per super-step. Cell (r, j):
// pair p = j>>1, tile = p>>6, l = p&63, s = r+l ->
//   nibble (s&1) of db[tile*TSB2 + (s>>1)*64 + l], bit pair (j&1)*2.
// ---------------------------------------------------------------------------
__global__ __launch_bounds__(512) void backtrack_kernel(
    const unsigned char* __restrict__ dec, const float* __restrict__ partV,
    const int* __restrict__ partJ, const float* __restrict__ y_t,
    float* __restrict__ w_vs, float* __restrict__ cost_out) {
  const int b = blockIdx.x;
  const int t = threadIdx.x;
  const int rowIdx = t >> 3;
  const int sub = t & 7;
  __shared__ unsigned short tab[64][BTP_ * 2 + 2];
  __shared__ unsigned short lastv[64][8];
  __shared__ int st_i, st_j;
  __shared__ int jrow[65];
  const unsigned char* db = dec + (size_t)b * 32 * TSB2_;
  const float* yt = y_t + b * M_;
  float* wv = w_vs + b * N_;

  if (t == 0) {
    float bc = finf(); int bj = 0;
    for (int c = 0; c < 4; ++c) {  // chunks ascend in j: strict < keeps first
      const float v = partV[b * 4 + c];
      if (v < bc) { bc = v; bj = partJ[b * 4 + c]; }
    }
    cost_out[b] = bc;
    st_i = N_ - 1;
    st_j = bj;
    wv[N_ - 1] = yt[bj];
  }
  for (;;) {
    __syncthreads();
    const int i = st_i, j = st_j;
    if (i <= 0) break;
    int plo = (j >> 1) - (BTP_ - 1);
    if (plo < 0) plo = 0;
    const int r = i - rowIdx;
    const int cbase = sub * 48;  // 24 pairs = 48 cells per sub-thread
    int patchEnd = 0;
    if (r >= 1) {
      unsigned char nb[24];
      const int p0 = plo + sub * 24;
#pragma unroll
      for (int k = 0; k < 24; ++k) {
        const int p = p0 + k;
        const int l = p & 63;
        const int s = r + l;
        const unsigned char by =
            db[(size_t)(p >> 6) * TSB2_ + (size_t)(s >> 1) * 64 + l];
        nb[k] = (by >> ((s & 1) * 4)) & 15;
      }
      unsigned int run = 0xFFFF;
      int fs = -1;
#pragma unroll
      for (int k = 0; k < 24; ++k) {
        const unsigned int nib = nb[k];
#pragma unroll
        for (int p2 = 0; p2 < 2; ++p2) {
          const unsigned int code = (nib >> (p2 * 2)) & 3u;
          const int cloc = 2 * k + p2;
          if (code != 2u) {
            run = (unsigned int)(((cbase + cloc) << 2) | code);
            if (fs < 0) fs = cloc;
          }
          tab[rowIdx][cbase + cloc] = (unsigned short)run;
        }
      }
      lastv[rowIdx][sub] = (unsigned short)run;
      patchEnd = (fs < 0) ? 48 : fs;
    }
    __syncthreads();
    if (r >= 1 && sub > 0 && patchEnd > 0) {
      unsigned short inc = 0xFFFF;
      for (int s2 = 0; s2 < sub; ++s2) {
        const unsigned short lv = lastv[rowIdx][s2];
        if (lv != 0xFFFF) inc = lv;
      }
      if (inc != 0xFFFF) {
        for (int k = 0; k < patchEnd; ++k) tab[rowIdx][cbase + k] = inc;
      }
    }
    __syncthreads();
    if (t == 0) {
      const int base = plo << 1;
      int rr = i, cj = j;
      while (rr >= 1 && (i - rr) < 64) {
        const int l = i - rr;
        const int c = cj - base;
        if (c < 0) break;  // window exhausted; restart super-step
        const unsigned short v = tab[l][c];
        if (v == 0xFFFF) { cj = base - 1; break; }  // left-run exits window
        cj = base + (int)(v >> 2) - (((v & 3) == 0) ? 1 : 0);
        --rr;
        jrow[i - rr] = cj;
      }
      st_i = rr;
      st_j = cj;
    }
    __syncthreads();
    const int cnt = i - st_i;
    if (t < cnt) wv[i - 1 - t] = yt[jrow[t + 1]];
  }
}

// ---------------------------------------------------------------------------
extern "C" void kernel_launch(void* const* d_in, const int* in_sizes, int n_in,
                              void* d_out, int out_size, void* d_ws, size_t ws_size,
                              hipStream_t stream) {
  const float* x = (const float*)d_in[0];
  const float* y = (const float*)d_in[1];
  const float* x_t = (const float*)d_in[2];
  const float* y_t = (const float*)d_in[3];

  float* out_cost = (float*)d_out;      // [B_]
  float* out_wts = out_cost + B_;       // [B_][N_]
  float* out_wvs = out_wts + B_ * N_;   // [B_][N_]

  const size_t csBytes = (size_t)B_ * 8 * TILEF_ * 4;   // 71.8 MB (one chunk)
  const size_t decBytes = (size_t)B_ * 32 * TSB2_;      // 17.96 MB
  const size_t x2Bytes = (size_t)B_ * N_ * 4;

  char* ws = (char*)d_ws;
  float* Cs = (float*)ws;
  unsigned char* dec = (unsigned char*)(ws + csBytes);
  float* x2 = (float*)(ws + csBytes + decBytes);
  float* carryA = (float*)(ws + csBytes + decBytes + x2Bytes);
  float* carryB = carryA + B_ * N_;
  float* partV = carryB + B_ * N_;
  int* partJ = (int*)(partV + B_ * 4);

  prep_kernel<<<dim3((B_ * N_) / 256), 256, 0, stream>>>(x, x_t, x2, out_wts);

  float* cbuf[2] = {carryA, carryB};
  for (int c = 0; c < 4; ++c) {
    gemm_kernel<<<dim3(4, N_ / 128, B_), 256, 0, stream>>>(x, y, x2, Cs, c);
    const float* cin = cbuf[(c + 1) & 1];
    float* cout = cbuf[c & 1];
    dtw_dp<<<dim3(B_), 512, 0, stream>>>(Cs, dec, cin, cout, partV, partJ, c,
                                         c > 0 ? 1 : 0);
  }

  backtrack_kernel<<<dim3(B_), 512, 0, stream>>>(dec, partV, partJ, y_t,
                                                 out_wvs, out_cost);
}

// Round 11
// 1494.074 us; speedup vs baseline: 1.2527x; 1.0250x over previous
//
#include <hip/hip_runtime.h>

#define B_ 16
#define N_ 1024
#define M_ 4096
#define D_ 64
#define NTW 8                          // waves per batch pipeline
#define TROWS_ 1112                    // padded skewed rows per 128-col tile
#define TILEF_ ((size_t)TROWS_ * 128)  // floats per tile buffer
#define TSBW_ ((size_t)136 * 64)       // dec u32 words per tile (8704)
#define BTP_ 192                       // backtrack window pairs (384 cells)

__device__ __forceinline__ float finf() { return __builtin_inff(); }

// wave-wide shift right by 1 lane; lane 0 gets old (0), always select-overridden.
__device__ __forceinline__ float wave_shr1(float x) {
  return __int_as_float(__builtin_amdgcn_update_dpp(
      0, __float_as_int(x), 0x138, 0xF, 0xF, false));
}
__device__ __forceinline__ float rdlane(float v, int l) {
  return __int_as_float(__builtin_amdgcn_readlane(__float_as_int(v), l));
}

// ---------------------------------------------------------------------------
__global__ void prep_kernel(const float* __restrict__ x,
                            const float* __restrict__ x_t,
                            float* __restrict__ x2,
                            float* __restrict__ w_ts_out) {
  int id = blockIdx.x * blockDim.x + threadIdx.x;
  const float4* xr = (const float4*)(x + (size_t)id * D_);
  float s = 0.f;
#pragma unroll
  for (int e = 0; e < D_ / 4; ++e) {
    float4 v = xr[e];
    s += v.x * v.x + v.y * v.y + v.z * v.z + v.w * v.w;
  }
  x2[id] = s;
  w_ts_out[id] = x_t[id];
}

// ---------------------------------------------------------------------------
// GEMM writing C skewed for cpl=2 tiles of 128 cols: cell (i, col ctt of
// tile) -> CsT[(i + (ctt>>1))*128 + ctt].
// ---------------------------------------------------------------------------
__global__ __launch_bounds__(256) void gemm_kernel(
    const float* __restrict__ x, const float* __restrict__ y,
    const float* __restrict__ x2, float* __restrict__ Cs, int chunk) {
  const int b = blockIdx.z;
  const int tb = blockIdx.x;               // 256-col block within chunk
  const int lane = threadIdx.x & 63;
  const int wid = threadIdx.x >> 6;
  const int ct = wid * 64 + lane;          // 0..255
  const int j = chunk * 1024 + tb * 256 + ct;
  const int tileIdx = tb * 2 + (ct >> 7);  // tile within chunk (0..7)
  const int ctt = ct & 127;
  const int l = ctt >> 1;
  float* CsT = Cs + (size_t)(b * 8 + tileIdx) * TILEF_;

  const float4* yrow = (const float4*)(y + ((size_t)b * M_ + j) * D_);
  float4 yr[D_ / 4];
#pragma unroll
  for (int e = 0; e < D_ / 4; ++e) yr[e] = yrow[e];
  float y2 = 0.f;
#pragma unroll
  for (int e = 0; e < D_ / 4; ++e)
    y2 += yr[e].x * yr[e].x + yr[e].y * yr[e].y + yr[e].z * yr[e].z + yr[e].w * yr[e].w;

  const int ibeg = blockIdx.y * 128;
  for (int i = ibeg; i < ibeg + 128; ++i) {
    const float4* xr = (const float4*)(x + ((size_t)b * N_ + i) * D_);
    float acc = 0.f;
#pragma unroll
    for (int e = 0; e < D_ / 4; ++e) {
      float4 xv = xr[e];
      acc += xv.x * yr[e].x + xv.y * yr[e].y + xv.z * yr[e].z + xv.w * yr[e].w;
    }
    CsT[(size_t)(i + l) * 128 + ctt] = x2[b * N_ + i] + y2 - 2.f * acc;
  }
}

// ---------------------------------------------------------------------------
// Systolic DP, cpl=2, 16-deep register prefetch (two 8-reg float2 banks).
// One batch per 512-thread WG (8 waves, 2/SIMD). Wave W owns a 128-col tile;
// lane l owns cols 2l,2l+1; step s => row i = s - lane. Full-column LDS edge
// ring, publish per 8 rows, poll once per 8-step block.
// dec: 4 bits/lane/step packed 8 steps per u32 (1 store / 8 steps / lane).
// ---------------------------------------------------------------------------
__global__ __launch_bounds__(512) void dtw_dp(
    const float* __restrict__ Cs, unsigned int* __restrict__ dec,
    const float* __restrict__ carryIn, float* __restrict__ carryOut,
    float* __restrict__ partV, int* __restrict__ partJ,
    int chunk, int hasCarry) {
  const int b = blockIdx.x;
  const int t = threadIdx.x;
  const int lane = t & 63;
  const int W = t >> 6;

  __shared__ float ring[NTW - 1][1024];
  __shared__ float cring[1024];
  __shared__ int prog[NTW - 1];
  __shared__ float redV[NTW];
  __shared__ int redJ[NTW];
  volatile int* vProg = prog;

  if (t < NTW - 1) prog[t] = -1;
  const float* cIn = carryIn + b * N_;
  if (hasCarry && t < 256) ((float4*)cring)[t] = ((const float4*)cIn)[t];
  __syncthreads();

  const float INF = finf();
  const float* tileBase = Cs + (size_t)(b * 8 + W) * TILEF_;
  const float* loadP = tileBase + 16 * 128;
  const int tileG = chunk * 8 + W;
  unsigned int* decW = dec + (size_t)(b * 32 + tileG) * TSBW_ + lane;
  float* carryB = carryOut + b * N_;
  const int jbase = tileG * 128 + lane * 2;
  const float* ringR = ring[W > 0 ? W - 1 : 0];
  volatile float* ringW = ring[W < NTW - 1 ? W : 0];
  const bool doCarry = (W == NTW - 1) && (chunk < 3);

  float2 cc0 = ((const float2*)(tileBase + 0 * 128))[lane];
  float2 cc1 = ((const float2*)(tileBase + 1 * 128))[lane];
  float2 cc2 = ((const float2*)(tileBase + 2 * 128))[lane];
  float2 cc3 = ((const float2*)(tileBase + 3 * 128))[lane];
  float2 cc4 = ((const float2*)(tileBase + 4 * 128))[lane];
  float2 cc5 = ((const float2*)(tileBase + 5 * 128))[lane];
  float2 cc6 = ((const float2*)(tileBase + 6 * 128))[lane];
  float2 cc7 = ((const float2*)(tileBase + 7 * 128))[lane];
  float2 cc8 = ((const float2*)(tileBase + 8 * 128))[lane];
  float2 cc9 = ((const float2*)(tileBase + 9 * 128))[lane];
  float2 cc10 = ((const float2*)(tileBase + 10 * 128))[lane];
  float2 cc11 = ((const float2*)(tileBase + 11 * 128))[lane];
  float2 cc12 = ((const float2*)(tileBase + 12 * 128))[lane];
  float2 cc13 = ((const float2*)(tileBase + 13 * 128))[lane];
  float2 cc14 = ((const float2*)(tileBase + 14 * 128))[lane];
  float2 cc15 = ((const float2*)(tileBase + 15 * 128))[lane];

  float edgeVec = INF, ePrev = INF;
  float up0 = 0.f, up1 = 0.f;
  float sh1 = INF, sh2 = INF;
  float fin0 = INF, fin1 = INF;
  float ebuf[8];

#define BLOCKHEAD()                                                           \
  {                                                                           \
    if (sb < N_) {                                                            \
      if (W > 0) {                                                            \
        int tgt = sb + 7;                                                     \
        if (tgt > N_ - 1) tgt = N_ - 1;                                       \
        while (vProg[W - 1] < tgt) __builtin_amdgcn_s_sleep(1);               \
        asm volatile("" ::: "memory");                                        \
        edgeVec = ringR[(sb - 1 + lane) & 1023];                              \
      } else if (hasCarry) {                                                  \
        edgeVec = cring[(sb - 1 + lane) & 1023];                              \
      }                                                                       \
      ePrev = rdlane(edgeVec, 0);                                             \
    }                                                                         \
  }

#define DPSTEP(KK, CCV, ROW0, FIN)                                           \
  {                                                                          \
    const float eL = rdlane(edgeVec, (KK) + 1);                              \
    const bool l0 = (lane == 0);                                             \
    const float left0 = l0 ? eL : sh1;                                       \
    const float diag0 = l0 ? ePrev : sh2;                                    \
    ePrev = eL;                                                              \
    float m = fminf(up0, left0);                                             \
    float bv = fminf(diag0, m);                                              \
    unsigned int pk = (diag0 <= m) ? 0u : ((up0 <= left0) ? 1u : 2u);        \
    if (ROW0) bv = (sb + (KK) == lane) ? 0.f : bv;                           \
    const float D0 = CCV.x + bv;                                             \
    m = fminf(up1, D0);                                                      \
    bv = fminf(up0, m);                                                      \
    pk |= ((up0 <= m) ? 0u : ((up1 <= D0) ? 1u : 2u)) << 2;                  \
    if (ROW0) bv = (sb + (KK) == lane) ? 0.f : bv;                           \
    const float D1 = CCV.y + bv;                                             \
    if ((KK) == 0) pkb = pk;                                                 \
    else pkb |= pk << (4 * (KK));                                            \
    if ((KK) == 7) decW[0] = pkb;                                            \
    ebuf[(KK)] = D1;                                                         \
    if (FIN) {                                                               \
      const bool lr = (sb + (KK) == 1023 + lane);                            \
      fin0 = lr ? D0 : fin0;                                                 \
      fin1 = lr ? D1 : fin1;                                                 \
    }                                                                        \
    sh2 = sh1;                                                               \
    sh1 = wave_shr1(D1);                                                     \
    up0 = D0; up1 = D1;                                                      \
    CCV = ((const float2*)(loadP + (KK) * 128))[lane];                       \
  }

#define BLOCKEND()                                                           \
  {                                                                          \
    const int rb = sb - 63;                                                  \
    if (W < NTW - 1) {                                                       \
      if (lane == 63 && rb > -8) {                                           \
        _Pragma("unroll") for (int k = 0; k < 8; ++k) {                      \
          const int r = rb + k;                                              \
          if ((unsigned)r < (unsigned)N_) ringW[r] = ebuf[k];                \
        }                                                                    \
        __builtin_amdgcn_s_waitcnt(0xC07F);                                  \
        int p = rb + 7;                                                      \
        if (p > N_ - 1) p = N_ - 1;                                          \
        if (p >= 0) vProg[W] = p;                                            \
      }                                                                      \
    } else if (doCarry) {                                                    \
      if (lane == 63 && rb > -8) {                                           \
        _Pragma("unroll") for (int k = 0; k < 8; ++k) {                      \
          const int r = rb + k;                                              \
          if ((unsigned)r < (unsigned)N_) carryB[r] = ebuf[k];               \
        }                                                                    \
      }                                                                      \
    }                                                                        \
    loadP += 8 * 128;                                                        \
    decW += 64;                                                              \
  }

#define STEP8A(R0, FN)                                                       \
  DPSTEP(0, cc0, R0, FN) DPSTEP(1, cc1, R0, FN) DPSTEP(2, cc2, R0, FN)       \
  DPSTEP(3, cc3, R0, FN) DPSTEP(4, cc4, R0, FN) DPSTEP(5, cc5, R0, FN)       \
  DPSTEP(6, cc6, R0, FN) DPSTEP(7, cc7, R0, FN)
#define STEP8B(R0, FN)                                                       \
  DPSTEP(0, cc8, R0, FN) DPSTEP(1, cc9, R0, FN) DPSTEP(2, cc10, R0, FN)      \
  DPSTEP(3, cc11, R0, FN) DPSTEP(4, cc12, R0, FN) DPSTEP(5, cc13, R0, FN)    \
  DPSTEP(6, cc14, R0, FN) DPSTEP(7, cc15, R0, FN)

#define ITER16(R0, FN)                                                       \
  {                                                                          \
    BLOCKHEAD();                                                             \
    { unsigned int pkb; STEP8A(R0, FN) }                                     \
    BLOCKEND();                                                              \
    sb += 8;                                                                 \
    BLOCKHEAD();                                                             \
    { unsigned int pkb; STEP8B(R0, FN) }                                     \
    BLOCKEND();                                                              \
    sb += 8;                                                                 \
  }

  int sb = 0;
  for (int it = 0; it < 4; ++it) ITER16(1, 0);    // sb 0..63: row-0 live
  for (int it = 0; it < 59; ++it) ITER16(0, 0);   // sb 64..1007: main
  for (int it = 0; it < 5; ++it) ITER16(0, 1);    // sb 1008..1087: fin
#undef DPSTEP
#undef STEP8A
#undef STEP8B
#undef ITER16
#undef BLOCKHEAD
#undef BLOCKEND

  float mv = fin0; int mj = jbase;
  if (fin1 < mv) { mv = fin1; mj = jbase + 1; }
#pragma unroll
  for (int off = 32; off > 0; off >>= 1) {
    const float ov = __shfl_down(mv, off);
    const int oj = __shfl_down(mj, off);
    if (ov < mv || (ov == mv && oj < mj)) { mv = ov; mj = oj; }
  }
  if (lane == 0) { redV[W] = mv; redJ[W] = mj; }
  __syncthreads();
  if (t == 0) {
    float bm = redV[0]; int bj = redJ[0];
#pragma unroll
    for (int w = 1; w < NTW; ++w)
      if (redV[w] < bm) { bm = redV[w]; bj = redJ[w]; }
    partV[b * 4 + chunk] = bm;
    partJ[b * 4 + chunk] = bj;
  }
}

// ---------------------------------------------------------------------------
// Backtrack: 512 threads = 8 subs/row x 64 rows per super-step. Cell (r, j):
// pair p = j>>1, tile = p>>6, l = p&63, s = r+l ->
//   nibble (s&7) of dw[tile*TSBW + (s>>3)*64 + l], bit pair (j&1)*2.
// ---------------------------------------------------------------------------
__global__ __launch_bounds__(512) void backtrack_kernel(
    const unsigned int* __restrict__ dec, const float* __restrict__ partV,
    const int* __restrict__ partJ, const float* __restrict__ y_t,
    float* __restrict__ w_vs, float* __restrict__ cost_out) {
  const int b = blockIdx.x;
  const int t = threadIdx.x;
  const int rowIdx = t >> 3;
  const int sub = t & 7;
  __shared__ unsigned short tab[64][BTP_ * 2 + 2];
  __shared__ unsigned short lastv[64][8];
  __shared__ int st_i, st_j;
  __shared__ int jrow[65];
  const unsigned int* dw = dec + (size_t)b * 32 * TSBW_;
  const float* yt = y_t + b * M_;
  float* wv = w_vs + b * N_;

  if (t == 0) {
    float bc = finf(); int bj = 0;
    for (int c = 0; c < 4; ++c) {  // chunks ascend in j: strict < keeps first
      const float v = partV[b * 4 + c];
      if (v < bc) { bc = v; bj = partJ[b * 4 + c]; }
    }
    cost_out[b] = bc;
    st_i = N_ - 1;
    st_j = bj;
    wv[N_ - 1] = yt[bj];
  }
  for (;;) {
    __syncthreads();
    const int i = st_i, j = st_j;
    if (i <= 0) break;
    int plo = (j >> 1) - (BTP_ - 1);
    if (plo < 0) plo = 0;
    const int r = i - rowIdx;
    const int cbase = sub * 48;  // 24 pairs = 48 cells per sub-thread
    int patchEnd = 0;
    if (r >= 1) {
      unsigned char nb[24];
      const int p0 = plo + sub * 24;
#pragma unroll
      for (int k = 0; k < 24; ++k) {
        const int p = p0 + k;
        const int l = p & 63;
        const int s = r + l;
        const unsigned int word =
            dw[(size_t)(p >> 6) * TSBW_ + (size_t)(s >> 3) * 64 + l];
        nb[k] = (word >> (4 * (s & 7))) & 15u;
      }
      unsigned int run = 0xFFFF;
      int fs = -1;
#pragma unroll
      for (int k = 0; k < 24; ++k) {
        const unsigned int nib = nb[k];
#pragma unroll
        for (int p2 = 0; p2 < 2; ++p2) {
          const unsigned int code = (nib >> (p2 * 2)) & 3u;
          const int cloc = 2 * k + p2;
          if (code != 2u) {
            run = (unsigned int)(((cbase + cloc) << 2) | code);
            if (fs < 0) fs = cloc;
          }
          tab[rowIdx][cbase + cloc] = (unsigned short)run;
        }
      }
      lastv[rowIdx][sub] = (unsigned short)run;
      patchEnd = (fs < 0) ? 48 : fs;
    }
    __syncthreads();
    if (r >= 1 && sub > 0 && patchEnd > 0) {
      unsigned short inc = 0xFFFF;
      for (int s2 = 0; s2 < sub; ++s2) {
        const unsigned short lv = lastv[rowIdx][s2];
        if (lv != 0xFFFF) inc = lv;
      }
      if (inc != 0xFFFF) {
        for (int k = 0; k < patchEnd; ++k) tab[rowIdx][cbase + k] = inc;
      }
    }
    __syncthreads();
    if (t == 0) {
      const int base = plo << 1;
      int rr = i, cj = j;
      while (rr >= 1 && (i - rr) < 64) {
        const int l = i - rr;
        const int c = cj - base;
        if (c < 0) break;  // window exhausted; restart super-step
        const unsigned short v = tab[l][c];
        if (v == 0xFFFF) { cj = base - 1; break; }  // left-run exits window
        cj = base + (int)(v >> 2) - (((v & 3) == 0) ? 1 : 0);
        --rr;
        jrow[i - rr] = cj;
      }
      st_i = rr;
      st_j = cj;
    }
    __syncthreads();
    const int cnt = i - st_i;
    if (t < cnt) wv[i - 1 - t] = yt[jrow[t + 1]];
  }
}

// ---------------------------------------------------------------------------
extern "C" void kernel_launch(void* const* d_in, const int* in_sizes, int n_in,
                              void* d_out, int out_size, void* d_ws, size_t ws_size,
                              hipStream_t stream) {
  const float* x = (const float*)d_in[0];
  const float* y = (const float*)d_in[1];
  const float* x_t = (const float*)d_in[2];
  const float* y_t = (const float*)d_in[3];

  float* out_cost = (float*)d_out;      // [B_]
  float* out_wts = out_cost + B_;       // [B_][N_]
  float* out_wvs = out_wts + B_ * N_;   // [B_][N_]

  const size_t csBytes = (size_t)B_ * 8 * TILEF_ * 4;   // 72.9 MB (one chunk)
  const size_t decBytes = (size_t)B_ * 32 * TSBW_ * 4;  // 17.8 MB
  const size_t x2Bytes = (size_t)B_ * N_ * 4;

  char* ws = (char*)d_ws;
  float* Cs = (float*)ws;
  unsigned int* dec = (unsigned int*)(ws + csBytes);
  float* x2 = (float*)(ws + csBytes + decBytes);
  float* carryA = (float*)(ws + csBytes + decBytes + x2Bytes);
  float* carryB = carryA + B_ * N_;
  float* partV = carryB + B_ * N_;
  int* partJ = (int*)(partV + B_ * 4);

  prep_kernel<<<dim3((B_ * N_) / 256), 256, 0, stream>>>(x, x_t, x2, out_wts);

  float* cbuf[2] = {carryA, carryB};
  for (int c = 0; c < 4; ++c) {
    gemm_kernel<<<dim3(4, N_ / 128, B_), 256, 0, stream>>>(x, y, x2, Cs, c);
    const float* cin = cbuf[(c + 1) & 1];
    float* cout = cbuf[c & 1];
    dtw_dp<<<dim3(B_), 512, 0, stream>>>(Cs, dec, cin, cout, partV, partJ, c,
                                         c > 0 ? 1 : 0);
  }

  backtrack_kernel<<<dim3(B_), 512, 0, stream>>>(dec, partV, partJ, y_t,
                                                 out_wvs, out_cost);
}